// Round 1
// baseline (10414.753 us; speedup 1.0000x reference)
//
#include <hip/hip_runtime.h>
#include <hip/hip_bf16.h>

// Problem constants
#define NB 32      // batch
#define TO 64      // output tokens
#define TT 65      // decode steps (To+1)
#define TI 512     // encoder time
#define VV 10000   // vocab
#define EE 512     // embed
#define HH 512     // hidden
#define G4 2048    // 4*H
#define SOS_ID 1
#define EOS_ID 2

// ---------------------------------------------------------------------------
// Weight transpose: Wt[k][j] = concat(A,B)[j][k], optionally zero-padded to Jp
// ---------------------------------------------------------------------------
__global__ void transpose_cat(const float* __restrict__ A, int KA,
                              const float* __restrict__ B, int KB,
                              int J, int Jp, float* __restrict__ Wt) {
    int K = KA + KB;
    long total = (long)K * Jp;
    for (long idx = (long)blockIdx.x * 256 + threadIdx.x; idx < total;
         idx += (long)gridDim.x * 256) {
        int j = (int)(idx % Jp);
        int k = (int)(idx / Jp);
        float v = 0.f;
        if (j < J) v = (k < KA) ? A[(long)j * KA + k] : B[(long)j * KB + (k - KA)];
        Wt[idx] = v;
    }
}

// ---------------------------------------------------------------------------
// Partial GEMM: part[ks][n][j] = sum_{k in chunk ks} x[n][k] * Wt[k][j]
// x is a virtual concat of up to 3 segments (each row-stride 512):
//   k in [0,KA): segment A (if tokens != nullptr, row = token id, else row = n)
//   k in [KA,KAB): segment B;   k in [KAB,K): segment C
// grid = (Jp/256, K/64), block = 256 (4 waves, each wave owns 64 consecutive j)
// ---------------------------------------------------------------------------
__global__ void gemm_part(const float* __restrict__ Wt, int Jp, int K,
                          const float* __restrict__ xA, int KA,
                          const float* __restrict__ xB, int KAB,
                          const float* __restrict__ xC,
                          const int* __restrict__ tokens, int t,
                          float* __restrict__ part) {
    __shared__ float xs[64 * 36];  // xt[k][n], stride 36 (pad: bank spread + 16B align)
    int k0 = blockIdx.y * 64;
    for (int idx = threadIdx.x; idx < 64 * 32; idx += 256) {
        int n = idx >> 6, k = idx & 63;
        int kk = k0 + k;
        float v;
        if (kk < KA) {
            int row = n;
            if (tokens) row = (t == 0) ? SOS_ID : tokens[n * TO + (t - 1)];
            v = xA[(long)row * 512 + kk];
        } else if (kk < KAB) {
            v = xB[n * 512 + (kk - KA)];
        } else {
            v = xC[n * 512 + (kk - KAB)];
        }
        xs[k * 36 + n] = v;
    }
    __syncthreads();

    int lane = threadIdx.x & 63;
    int j = blockIdx.x * 256 + (threadIdx.x >> 6) * 64 + lane;
    float acc[32];
#pragma unroll
    for (int q = 0; q < 32; q++) acc[q] = 0.f;

    const float* wp = Wt + (long)k0 * Jp + j;
    for (int k = 0; k < 64; k++) {
        float w = wp[(long)k * Jp];
        const float4* xv = (const float4*)(xs + k * 36);
#pragma unroll
        for (int q = 0; q < 8; q++) {
            float4 x4 = xv[q];
            acc[4 * q + 0] += w * x4.x;
            acc[4 * q + 1] += w * x4.y;
            acc[4 * q + 2] += w * x4.z;
            acc[4 * q + 3] += w * x4.w;
        }
    }
    float* po = part + (long)blockIdx.y * 32 * Jp + j;
#pragma unroll
    for (int nn = 0; nn < 32; nn++) po[(long)nn * Jp] = acc[nn];
}

// ---------------------------------------------------------------------------
// LSTM gates: sum k-split partials (Jp=2048) + biases, apply i,f,g,o gating
// ---------------------------------------------------------------------------
__global__ void lstm_gates(const float* __restrict__ part, int KS,
                           const float* __restrict__ bi, const float* __restrict__ bh,
                           float* __restrict__ h, float* __restrict__ c) {
    int idx = blockIdx.x * 256 + threadIdx.x;  // over N*H = 16384
    int n = idx >> 9, m = idx & 511;
    float gi = bi[m] + bh[m];
    float gf = bi[512 + m] + bh[512 + m];
    float gg = bi[1024 + m] + bh[1024 + m];
    float go = bi[1536 + m] + bh[1536 + m];
    for (int s = 0; s < KS; s++) {
        const float* p = part + ((long)s * 32 + n) * G4;
        gi += p[m];
        gf += p[512 + m];
        gg += p[1024 + m];
        go += p[1536 + m];
    }
    float cv = c[idx];
    float si = 1.f / (1.f + expf(-gi));
    float sf = 1.f / (1.f + expf(-gf));
    float so = 1.f / (1.f + expf(-go));
    float c2 = sf * cv + si * tanhf(gg);
    c[idx] = c2;
    h[idx] = so * tanhf(c2);
}

// ---------------------------------------------------------------------------
// Generic k-split reduce + bias (+optional tanh); guards j < J (Jp padding)
// out[n*ldo + j]
// ---------------------------------------------------------------------------
__global__ void reduce_bias(const float* __restrict__ part, int KS, int Jp, int J,
                            const float* __restrict__ bias, float* __restrict__ out,
                            long ldo, int act) {
    long idx = (long)blockIdx.x * 256 + threadIdx.x;
    if (idx >= (long)32 * J) return;
    int n = (int)(idx / J), j = (int)(idx % J);
    float s = bias[j];
    for (int ks = 0; ks < KS; ks++) s += part[((long)ks * 32 + n) * Jp + j];
    if (act) s = tanhf(s);
    out[(long)n * ldo + j] = s;
}

// ---------------------------------------------------------------------------
// Attention scores: scores[n][ti] = dot(h2[n], enc[n][ti]); wave per ti
// grid = (8, 32): x = ti-chunk of 64, y = n
// ---------------------------------------------------------------------------
__global__ void attn_scores(const float* __restrict__ enc, const float* __restrict__ h2,
                            float* __restrict__ scores) {
    int n = blockIdx.y;
    int lane = threadIdx.x & 63, wv = threadIdx.x >> 6;
    const float* r = h2 + n * HH;
    float4 r0 = *(const float4*)(r + lane * 8);
    float4 r1 = *(const float4*)(r + lane * 8 + 4);
    for (int i = 0; i < 16; i++) {
        int ti = blockIdx.x * 64 + wv * 16 + i;
        const float* e = enc + ((long)n * TI + ti) * HH + lane * 8;
        float4 e0 = *(const float4*)e;
        float4 e1 = *(const float4*)(e + 4);
        float s = r0.x * e0.x + r0.y * e0.y + r0.z * e0.z + r0.w * e0.w +
                  r1.x * e1.x + r1.y * e1.y + r1.z * e1.z + r1.w * e1.w;
        s += __shfl_xor(s, 32);
        s += __shfl_xor(s, 16);
        s += __shfl_xor(s, 8);
        s += __shfl_xor(s, 4);
        s += __shfl_xor(s, 2);
        s += __shfl_xor(s, 1);
        if (lane == 0) scores[n * TI + ti] = s;
    }
}

// ---------------------------------------------------------------------------
// Softmax (recomputed per block, cheap) + weighted sum over enc -> att_c
// grid = (4, 32): x = h-chunk of 128, y = n
// ---------------------------------------------------------------------------
__global__ void attn_softapply(const float* __restrict__ enc,
                               const float* __restrict__ scores,
                               float* __restrict__ attc) {
    __shared__ float wl[512];
    __shared__ float red[256];
    __shared__ float prt[256];
    int n = blockIdx.y, tid = threadIdx.x;
    float a = scores[n * TI + tid], b = scores[n * TI + 256 + tid];
    float m = fmaxf(a, b);
    red[tid] = m;
    __syncthreads();
    for (int s = 128; s > 0; s >>= 1) {
        if (tid < s) red[tid] = fmaxf(red[tid], red[tid + s]);
        __syncthreads();
    }
    m = red[0];
    __syncthreads();
    float ea = expf(a - m), eb = expf(b - m);
    red[tid] = ea + eb;
    __syncthreads();
    for (int s = 128; s > 0; s >>= 1) {
        if (tid < s) red[tid] += red[tid + s];
        __syncthreads();
    }
    float inv = 1.f / red[0];
    wl[tid] = ea * inv;
    wl[256 + tid] = eb * inv;
    __syncthreads();

    int h = blockIdx.x * 128 + (tid & 127);
    int half = tid >> 7;
    const float* e = enc + ((long)n * TI + half * 256) * HH + h;
    float acc = 0.f;
#pragma unroll 4
    for (int ti = 0; ti < 256; ti++) acc += wl[half * 256 + ti] * e[(long)ti * HH];
    prt[tid] = acc;
    __syncthreads();
    if (half == 0) attc[n * HH + h] = prt[tid] + prt[tid + 128];
}

// ---------------------------------------------------------------------------
// Loss: per-(n,t) logsumexp NLL, then mean
// ---------------------------------------------------------------------------
__global__ void loss_rows(const float* __restrict__ out, const int* __restrict__ tokens,
                          float* __restrict__ nll) {
    __shared__ float red[256];
    int row = blockIdx.x;  // n*TT + t
    int n = row / TT, t = row % TT;
    const float* y = out + (long)row * VV;
    int tid = threadIdx.x;
    float m = -1e30f;
    for (int v = tid; v < VV; v += 256) m = fmaxf(m, y[v]);
    red[tid] = m;
    __syncthreads();
    for (int s = 128; s > 0; s >>= 1) {
        if (tid < s) red[tid] = fmaxf(red[tid], red[tid + s]);
        __syncthreads();
    }
    m = red[0];
    __syncthreads();
    float sum = 0.f;
    for (int v = tid; v < VV; v += 256) sum += expf(y[v] - m);
    red[tid] = sum;
    __syncthreads();
    for (int s = 128; s > 0; s >>= 1) {
        if (tid < s) red[tid] += red[tid + s];
        __syncthreads();
    }
    if (tid == 0) {
        int target = (t < TO) ? tokens[n * TO + t] : EOS_ID;
        float lse = m + logf(red[0]);
        nll[row] = lse - y[target];
    }
}

__global__ void loss_final(const float* __restrict__ nll, float* __restrict__ out_loss) {
    __shared__ float red[256];
    int tid = threadIdx.x;
    float s = 0.f;
    for (int i = tid; i < NB * TT; i += 256) s += nll[i];
    red[tid] = s;
    __syncthreads();
    for (int k = 128; k > 0; k >>= 1) {
        if (tid < k) red[tid] += red[tid + k];
        __syncthreads();
    }
    if (tid == 0) *out_loss = red[0] / (float)(NB * TT);
}

// ---------------------------------------------------------------------------
extern "C" void kernel_launch(void* const* d_in, const int* in_sizes, int n_in,
                              void* d_out, int out_size, void* d_ws, size_t ws_size,
                              hipStream_t stream) {
    const int* padded   = (const int*)d_in[0];
    const float* enc    = (const float*)d_in[1];
    const float* emb    = (const float*)d_in[2];
    const float* W_ih0  = (const float*)d_in[3];
    const float* W_hh0  = (const float*)d_in[4];
    const float* b_ih0  = (const float*)d_in[5];
    const float* b_hh0  = (const float*)d_in[6];
    const float* W_ih_r = (const float*)d_in[7];
    const float* W_hh_r = (const float*)d_in[8];
    const float* b_ih_r = (const float*)d_in[9];
    const float* b_hh_r = (const float*)d_in[10];
    const float* W1     = (const float*)d_in[11];
    const float* b1     = (const float*)d_in[12];
    const float* W2     = (const float*)d_in[13];
    const float* b2     = (const float*)d_in[14];
    float* out = (float*)d_out;
    float* ws  = (float*)d_ws;

    // workspace layout (floats)
    float* Wt0  = ws;                   // [1536][2048]
    float* Wt1  = Wt0 + 1536 * 2048;    // [1024][2048]
    float* Wt2  = Wt1 + 1024 * 2048;    // [1024][2048]
    float* Wm1  = Wt2 + 1024 * 2048;    // [1024][512]
    float* Wm2  = Wm1 + 1024 * 512;     // [512][10240]  (padded vocab-ish cols)
    float* hbuf = Wm2 + 512 * 10240;    // [3][32][512]
    float* cbuf = hbuf + 3 * NB * HH;   // [3][32][512]
    float* attc = cbuf + 3 * NB * HH;   // [32][512]
    float* scor = attc + NB * HH;       // [32][512]
    float* y1   = scor + NB * TI;       // [32][512]
    float* gprt = y1 + NB * HH;         // max 8*32*10240 = 2,621,440
    float* nll  = gprt + 2621440;       // [2080]

    // one-time: zero recurrent state, transpose weights
    hipMemsetAsync(hbuf, 0, (size_t)(3 * NB * HH * 2 + NB * HH) * sizeof(float), stream);
    transpose_cat<<<2048, 256, 0, stream>>>(W_ih0, 1024, W_hh0, 512, G4, G4, Wt0);
    transpose_cat<<<2048, 256, 0, stream>>>(W_ih_r, 512, W_hh_r, 512, G4, G4, Wt1);
    transpose_cat<<<2048, 256, 0, stream>>>(W_ih_r + 2048 * 512, 512,
                                            W_hh_r + 2048 * 512, 512, G4, G4, Wt2);
    transpose_cat<<<1024, 256, 0, stream>>>(W1, 1024, nullptr, 0, 512, 512, Wm1);
    transpose_cat<<<2048, 256, 0, stream>>>(W2, 512, nullptr, 0, VV, 10240, Wm2);

    float* h0 = hbuf;
    float* h1 = hbuf + NB * HH;
    float* h2 = hbuf + 2 * NB * HH;
    float* c0 = cbuf;
    float* c1 = cbuf + NB * HH;
    float* c2 = cbuf + 2 * NB * HH;

    for (int t = 0; t < TT; t++) {
        // layer 0: x = [emb[tok], attc, h0], K=1536
        gemm_part<<<dim3(8, 24), 256, 0, stream>>>(Wt0, G4, 1536, emb, 512, attc, 1024,
                                                   h0, padded, t, gprt);
        lstm_gates<<<64, 256, 0, stream>>>(gprt, 24, b_ih0, b_hh0, h0, c0);
        // layer 1: x = [h0', h1], K=1024
        gemm_part<<<dim3(8, 16), 256, 0, stream>>>(Wt1, G4, 1024, h0, 512, h1, 1024,
                                                   nullptr, nullptr, 0, gprt);
        lstm_gates<<<64, 256, 0, stream>>>(gprt, 16, b_ih_r, b_hh_r, h1, c1);
        // layer 2: x = [h1', h2], K=1024
        gemm_part<<<dim3(8, 16), 256, 0, stream>>>(Wt2, G4, 1024, h1, 512, h2, 1024,
                                                   nullptr, nullptr, 0, gprt);
        lstm_gates<<<64, 256, 0, stream>>>(gprt, 16, b_ih_r + G4, b_hh_r + G4, h2, c2);
        // attention
        attn_scores<<<dim3(8, 32), 256, 0, stream>>>(enc, h2, scor);
        attn_softapply<<<dim3(4, 32), 256, 0, stream>>>(enc, scor, attc);
        // MLP1: x = [h2', attc], K=1024, J=512, tanh
        gemm_part<<<dim3(2, 16), 256, 0, stream>>>(Wm1, 512, 1024, h2, 512, attc, 1024,
                                                   nullptr, nullptr, 0, gprt);
        reduce_bias<<<64, 256, 0, stream>>>(gprt, 16, 512, 512, b1, y1, 512, 1);
        // MLP2: x = y1, K=512, J=10000 (padded 10240), straight into d_out
        gemm_part<<<dim3(40, 8), 256, 0, stream>>>(Wm2, 10240, 512, y1, 512, nullptr,
                                                   512, nullptr, nullptr, 0, gprt);
        reduce_bias<<<1250, 256, 0, stream>>>(gprt, 8, 10240, VV, b2,
                                              out + (long)t * VV, (long)TT * VV, 0);
    }

    loss_rows<<<NB * TT, 256, 0, stream>>>(out, padded, nll);
    loss_final<<<1, 256, 0, stream>>>(nll, out + (long)NB * TT * VV);
}

// Round 2
// 7652.949 us; speedup vs baseline: 1.3609x; 1.3609x over previous
//
#include <hip/hip_runtime.h>
#include <hip/hip_bf16.h>

// Problem constants
#define NB 32      // batch
#define TO 64      // output tokens
#define TT 65      // decode steps (To+1)
#define TI 512     // encoder time
#define VV 10000   // vocab
#define EE 512     // embed
#define HH 512     // hidden
#define G4 2048    // 4*H
#define SOS_ID 1
#define EOS_ID 2

// ---------------------------------------------------------------------------
// Weight transpose: Wt[k][j] = concat(A,B)[j][k], zero-padded to Jp columns
// ---------------------------------------------------------------------------
__global__ void transpose_cat(const float* __restrict__ A, int KA,
                              const float* __restrict__ B, int KB,
                              int J, int Jp, float* __restrict__ Wt) {
    int K = KA + KB;
    long total = (long)K * Jp;
    for (long idx = (long)blockIdx.x * 256 + threadIdx.x; idx < total;
         idx += (long)gridDim.x * 256) {
        int j = (int)(idx % Jp);
        int k = (int)(idx / Jp);
        float v = 0.f;
        if (j < J) v = (k < KA) ? A[(long)j * KA + k] : B[(long)j * KB + (k - KA)];
        Wt[idx] = v;
    }
}

// ---------------------------------------------------------------------------
// Partial GEMM: part[ks][n][j] = sum_{k in chunk ks} x[n][k] * Wt[k][j]
// x = virtual concat of up to 3 segments (row-stride 512):
//   [0,KA): xA (tokens!=nullptr -> embedding row lookup), [KA,KAB): xB, rest xC
// grid = (Jp/256, K/64), block = 256
// ---------------------------------------------------------------------------
__global__ void gemm_part(const float* __restrict__ Wt, int Jp, int K,
                          const float* __restrict__ xA, int KA,
                          const float* __restrict__ xB, int KAB,
                          const float* __restrict__ xC,
                          const int* __restrict__ tokens, int t,
                          float* __restrict__ part) {
    __shared__ float xs[64 * 36];  // xt[k][n], stride 36
    int k0 = blockIdx.y * 64;
    for (int idx = threadIdx.x; idx < 64 * 32; idx += 256) {
        int n = idx >> 6, k = idx & 63;
        int kk = k0 + k;
        float v;
        if (kk < KA) {
            int row = n;
            if (tokens) row = (t == 0) ? SOS_ID : tokens[n * TO + (t - 1)];
            v = xA[(long)row * 512 + kk];
        } else if (kk < KAB) {
            v = xB[n * 512 + (kk - KA)];
        } else {
            v = xC[n * 512 + (kk - KAB)];
        }
        xs[k * 36 + n] = v;
    }
    __syncthreads();

    int lane = threadIdx.x & 63;
    int j = blockIdx.x * 256 + (threadIdx.x >> 6) * 64 + lane;
    float acc[32];
#pragma unroll
    for (int q = 0; q < 32; q++) acc[q] = 0.f;

    const float* wp = Wt + (long)k0 * Jp + j;
#pragma unroll 4
    for (int k = 0; k < 64; k++) {
        float w = wp[(long)k * Jp];
        const float4* xv = (const float4*)(xs + k * 36);
#pragma unroll
        for (int q = 0; q < 8; q++) {
            float4 x4 = xv[q];
            acc[4 * q + 0] += w * x4.x;
            acc[4 * q + 1] += w * x4.y;
            acc[4 * q + 2] += w * x4.z;
            acc[4 * q + 3] += w * x4.w;
        }
    }
    float* po = part + (long)blockIdx.y * 32 * Jp + j;
#pragma unroll
    for (int nn = 0; nn < 32; nn++) po[(long)nn * Jp] = acc[nn];
}

// ---------------------------------------------------------------------------
// LSTM gates: sum k-split partials + biases, apply i,f,g,o; optional h copy-out
// ---------------------------------------------------------------------------
__global__ void lstm_gates(const float* __restrict__ part, int KS,
                           const float* __restrict__ bi, const float* __restrict__ bh,
                           float* __restrict__ h, float* __restrict__ c,
                           float* __restrict__ hextra) {
    int idx = blockIdx.x * 256 + threadIdx.x;  // over N*H = 16384
    int n = idx >> 9, m = idx & 511;
    float gi = bi[m] + bh[m];
    float gf = bi[512 + m] + bh[512 + m];
    float gg = bi[1024 + m] + bh[1024 + m];
    float go = bi[1536 + m] + bh[1536 + m];
    for (int s = 0; s < KS; s++) {
        const float* p = part + ((long)s * 32 + n) * G4;
        gi += p[m];
        gf += p[512 + m];
        gg += p[1024 + m];
        go += p[1536 + m];
    }
    float cv = c[idx];
    float si = 1.f / (1.f + expf(-gi));
    float sf = 1.f / (1.f + expf(-gf));
    float so = 1.f / (1.f + expf(-go));
    float c2 = sf * cv + si * tanhf(gg);
    c[idx] = c2;
    float hv = so * tanhf(c2);
    h[idx] = hv;
    if (hextra) hextra[(long)n * 1024 + m] = hv;
}

// ---------------------------------------------------------------------------
// Fused attention: scores + softmax + weighted sum. One block (512 thr) per n.
// Writes attc (working buffer) and attc2 = mlpin[t][n][512..1024).
// ---------------------------------------------------------------------------
__global__ void attn_fused(const float* __restrict__ enc, const float* __restrict__ h2v,
                           float* __restrict__ attc, float* __restrict__ attc2) {
    __shared__ float sc[512];
    __shared__ float red[512];
    __shared__ float prt[4 * 512];
    int n = blockIdx.x, tid = threadIdx.x;

    // scores: thread owns ti = tid
    {
        const float* e = enc + ((long)n * TI + tid) * HH;
        const float* r = h2v + n * HH;
        float s = 0.f;
#pragma unroll 8
        for (int h = 0; h < HH; h += 4) {
            float4 e4 = *(const float4*)(e + h);
            float4 r4 = *(const float4*)(r + h);
            s += e4.x * r4.x + e4.y * r4.y + e4.z * r4.z + e4.w * r4.w;
        }
        sc[tid] = s;
    }
    __syncthreads();
    red[tid] = sc[tid];
    __syncthreads();
    for (int s = 256; s > 0; s >>= 1) {
        if (tid < s) red[tid] = fmaxf(red[tid], red[tid + s]);
        __syncthreads();
    }
    float m = red[0];
    __syncthreads();
    float ev = expf(sc[tid] - m);
    red[tid] = ev;
    __syncthreads();
    for (int s = 256; s > 0; s >>= 1) {
        if (tid < s) red[tid] += red[tid + s];
        __syncthreads();
    }
    float inv = 1.f / red[0];
    __syncthreads();
    sc[tid] = ev * inv;
    __syncthreads();

    // apply: 4 ti-groups x 128 h-threads (4 h each, float4)
    int h4 = (tid & 127) * 4;
    int g = tid >> 7;
    float4 a = {0.f, 0.f, 0.f, 0.f};
    const float* eb = enc + ((long)n * TI + g * 128) * HH + h4;
#pragma unroll 4
    for (int ti = 0; ti < 128; ti++) {
        float w = sc[g * 128 + ti];
        float4 e4 = *(const float4*)(eb + (long)ti * HH);
        a.x += w * e4.x;
        a.y += w * e4.y;
        a.z += w * e4.z;
        a.w += w * e4.w;
    }
    *(float4*)(prt + g * 512 + h4) = a;
    __syncthreads();
    if (g == 0) {
        float4 t0 = *(float4*)(prt + h4);
        float4 t1 = *(float4*)(prt + 512 + h4);
        float4 t2 = *(float4*)(prt + 1024 + h4);
        float4 t3 = *(float4*)(prt + 1536 + h4);
        float4 r;
        r.x = t0.x + t1.x + t2.x + t3.x;
        r.y = t0.y + t1.y + t2.y + t3.y;
        r.z = t0.z + t1.z + t2.z + t3.z;
        r.w = t0.w + t1.w + t2.w + t3.w;
        *(float4*)(attc + n * HH + h4) = r;
        *(float4*)(attc2 + (long)n * 1024 + h4) = r;
    }
}

// ---------------------------------------------------------------------------
// Full-K batched GEMM with fused bias(+tanh). Thread owns 2 j's (j0, j0+64).
// X rows contiguous [M][K], block row-group = blockIdx.y (32 rows).
// remap=0: out[row][J] (row = m0+nn, ld J); remap=1: out[(nn*TT+t)*VV + j]
// grid = (Jp/512, 65), block 256
// ---------------------------------------------------------------------------
__global__ void gemm_full(const float* __restrict__ Wt, int Jp, int J, int K,
                          const float* __restrict__ X,
                          const float* __restrict__ bias,
                          float* __restrict__ out, int act, int remap) {
    __shared__ float xs[64 * 36];
    int t = blockIdx.y;
    int m0 = t * 32;
    int lane = threadIdx.x & 63;
    int wv = threadIdx.x >> 6;
    int j0 = blockIdx.x * 512 + wv * 128 + lane;
    float acc0[32], acc1[32];
#pragma unroll
    for (int q = 0; q < 32; q++) { acc0[q] = 0.f; acc1[q] = 0.f; }

    for (int kc = 0; kc < K; kc += 64) {
        __syncthreads();
        for (int idx = threadIdx.x; idx < 64 * 32; idx += 256) {
            int n = idx >> 6, k = idx & 63;
            xs[k * 36 + n] = X[(long)(m0 + n) * K + kc + k];
        }
        __syncthreads();
        const float* wp = Wt + (long)kc * Jp + j0;
#pragma unroll 4
        for (int k = 0; k < 64; k++) {
            float w0 = wp[(long)k * Jp];
            float w1 = wp[(long)k * Jp + 64];
            const float4* xv = (const float4*)(xs + k * 36);
#pragma unroll
            for (int q = 0; q < 8; q++) {
                float4 x4 = xv[q];
                acc0[4 * q + 0] += w0 * x4.x;
                acc0[4 * q + 1] += w0 * x4.y;
                acc0[4 * q + 2] += w0 * x4.z;
                acc0[4 * q + 3] += w0 * x4.w;
                acc1[4 * q + 0] += w1 * x4.x;
                acc1[4 * q + 1] += w1 * x4.y;
                acc1[4 * q + 2] += w1 * x4.z;
                acc1[4 * q + 3] += w1 * x4.w;
            }
        }
    }
#pragma unroll
    for (int nn = 0; nn < 32; nn++) {
        long row = remap ? ((long)nn * TT + t) : (long)(m0 + nn);
        float* po = out + row * (remap ? (long)VV : (long)J);
        int ja = j0, jb = j0 + 64;
        if (ja < J) {
            float v = acc0[nn] + bias[ja];
            if (act) v = tanhf(v);
            po[ja] = v;
        }
        if (jb < J) {
            float v = acc1[nn] + bias[jb];
            if (act) v = tanhf(v);
            po[jb] = v;
        }
    }
}

// ---------------------------------------------------------------------------
// Loss: per-(n,t) logsumexp NLL, then mean
// ---------------------------------------------------------------------------
__global__ void loss_rows(const float* __restrict__ out, const int* __restrict__ tokens,
                          float* __restrict__ nll) {
    __shared__ float red[256];
    int row = blockIdx.x;  // n*TT + t
    int n = row / TT, t = row % TT;
    const float* y = out + (long)row * VV;
    int tid = threadIdx.x;
    float m = -1e30f;
    for (int v = tid; v < VV; v += 256) m = fmaxf(m, y[v]);
    red[tid] = m;
    __syncthreads();
    for (int s = 128; s > 0; s >>= 1) {
        if (tid < s) red[tid] = fmaxf(red[tid], red[tid + s]);
        __syncthreads();
    }
    m = red[0];
    __syncthreads();
    float sum = 0.f;
    for (int v = tid; v < VV; v += 256) sum += expf(y[v] - m);
    red[tid] = sum;
    __syncthreads();
    for (int s = 128; s > 0; s >>= 1) {
        if (tid < s) red[tid] += red[tid + s];
        __syncthreads();
    }
    if (tid == 0) {
        int target = (t < TO) ? tokens[n * TO + t] : EOS_ID;
        float lse = m + logf(red[0]);
        nll[row] = lse - y[target];
    }
}

__global__ void loss_final(const float* __restrict__ nll, float* __restrict__ out_loss) {
    __shared__ float red[256];
    int tid = threadIdx.x;
    float s = 0.f;
    for (int i = tid; i < NB * TT; i += 256) s += nll[i];
    red[tid] = s;
    __syncthreads();
    for (int k = 128; k > 0; k >>= 1) {
        if (tid < k) red[tid] += red[tid + k];
        __syncthreads();
    }
    if (tid == 0) *out_loss = red[0] / (float)(NB * TT);
}

// ---------------------------------------------------------------------------
extern "C" void kernel_launch(void* const* d_in, const int* in_sizes, int n_in,
                              void* d_out, int out_size, void* d_ws, size_t ws_size,
                              hipStream_t stream) {
    const int* padded   = (const int*)d_in[0];
    const float* enc    = (const float*)d_in[1];
    const float* emb    = (const float*)d_in[2];
    const float* W_ih0  = (const float*)d_in[3];
    const float* W_hh0  = (const float*)d_in[4];
    const float* b_ih0  = (const float*)d_in[5];
    const float* b_hh0  = (const float*)d_in[6];
    const float* W_ih_r = (const float*)d_in[7];
    const float* W_hh_r = (const float*)d_in[8];
    const float* b_ih_r = (const float*)d_in[9];
    const float* b_hh_r = (const float*)d_in[10];
    const float* W1     = (const float*)d_in[11];
    const float* b1     = (const float*)d_in[12];
    const float* W2     = (const float*)d_in[13];
    const float* b2     = (const float*)d_in[14];
    float* out = (float*)d_out;
    float* ws  = (float*)d_ws;

    // workspace layout (floats), total 15,353,888 (61.4 MB)
    float* Wt0  = ws;                   // [1536][2048]
    float* Wt1  = Wt0 + 1536 * 2048;    // [1024][2048]
    float* Wt2  = Wt1 + 1024 * 2048;    // [1024][2048]
    float* Wm1  = Wt2 + 1024 * 2048;    // [1024][512]
    float* R    = Wm1 + 1024 * 512;     // max(gprt 24*32*2048, Wm2 512*10240) = 5,242,880
    float* hbuf = R + 512 * 10240;      // [3][32][512]
    float* cbuf = hbuf + 3 * NB * HH;   // [3][32][512]
    float* attc = cbuf + 3 * NB * HH;   // [32][512]
    float* mlpin= attc + NB * HH;       // [65][32][1024]
    float* nll  = mlpin + TT * NB * 1024; // [2080]
    float* gprt = R;                    // loop-phase alias
    float* Wm2  = R;                    // final-phase alias (gprt dead)
    float* y1all= Wt0;                  // final-phase alias (Wt0 dead): [2080][512]

    // one-time: zero recurrent state, transpose recurrent weights
    hipMemsetAsync(hbuf, 0, (size_t)(3 * NB * HH * 2 + NB * HH) * sizeof(float), stream);
    transpose_cat<<<2048, 256, 0, stream>>>(W_ih0, 1024, W_hh0, 512, G4, G4, Wt0);
    transpose_cat<<<2048, 256, 0, stream>>>(W_ih_r, 512, W_hh_r, 512, G4, G4, Wt1);
    transpose_cat<<<2048, 256, 0, stream>>>(W_ih_r + 2048 * 512, 512,
                                            W_hh_r + 2048 * 512, 512, G4, G4, Wt2);
    transpose_cat<<<1024, 256, 0, stream>>>(W1, 1024, nullptr, 0, 512, 512, Wm1);

    float* h0 = hbuf;
    float* h1 = hbuf + NB * HH;
    float* h2 = hbuf + 2 * NB * HH;
    float* c0 = cbuf;
    float* c1 = cbuf + NB * HH;
    float* c2 = cbuf + 2 * NB * HH;

    for (int t = 0; t < TT; t++) {
        float* mrow = mlpin + (long)t * NB * 1024;
        // layer 0: x = [emb[tok], attc, h0], K=1536
        gemm_part<<<dim3(8, 24), 256, 0, stream>>>(Wt0, G4, 1536, emb, 512, attc, 1024,
                                                   h0, padded, t, gprt);
        lstm_gates<<<64, 256, 0, stream>>>(gprt, 24, b_ih0, b_hh0, h0, c0, nullptr);
        // layer 1: x = [h0', h1], K=1024
        gemm_part<<<dim3(8, 16), 256, 0, stream>>>(Wt1, G4, 1024, h0, 512, h1, 1024,
                                                   nullptr, nullptr, 0, gprt);
        lstm_gates<<<64, 256, 0, stream>>>(gprt, 16, b_ih_r, b_hh_r, h1, c1, nullptr);
        // layer 2: x = [h1', h2], K=1024; h2' also copied into mlpin[t][:][0:512]
        gemm_part<<<dim3(8, 16), 256, 0, stream>>>(Wt2, G4, 1024, h1, 512, h2, 1024,
                                                   nullptr, nullptr, 0, gprt);
        lstm_gates<<<64, 256, 0, stream>>>(gprt, 16, b_ih_r + G4, b_hh_r + G4, h2, c2,
                                           mrow);
        // fused attention -> attc and mlpin[t][:][512:1024]
        attn_fused<<<32, 512, 0, stream>>>(enc, h2, attc, mrow + 512);
    }

    // deferred MLP over all 2080 rows
    transpose_cat<<<2048, 256, 0, stream>>>(W2, 512, nullptr, 0, VV, 10240, Wm2);
    gemm_full<<<dim3(1, TT), 256, 0, stream>>>(Wm1, 512, 512, 1024, mlpin, b1,
                                               y1all, 1, 0);
    gemm_full<<<dim3(20, TT), 256, 0, stream>>>(Wm2, 10240, VV, 512, y1all, b2,
                                                out, 0, 1);
    loss_rows<<<NB * TT, 256, 0, stream>>>(out, padded, nll);
    loss_final<<<1, 256, 0, stream>>>(nll, out + (long)NB * TT * VV);
}